// Round 10
// baseline (1092.005 us; speedup 1.0000x reference)
//
#include <hip/hip_runtime.h>

#define N_NODES 100000
#define N_EDGES 500000
#define N_GRAPHS 100
#define DIM 146
#define APAD 160        // padded bf16 row stride (16B-aligned, 5 k-chunks of 32)
#define HPAD 160        // padded fp32 h row stride (640 B, 16B-aligned)
#define BN_EPS 1e-5f
#define GS_PART 8
#define GS_STRIDE 147   // 146 cols + 1 count slot
#define ST_PART 4       // stat-atomic partitions
#define GRID_GB 782     // (N_NODES+127)/128 ; must be <= 256 CUs * 4 blocks/CU

typedef __bf16 bf16x8 __attribute__((ext_vector_type(8)));
typedef float floatx4 __attribute__((ext_vector_type(4)));
typedef unsigned short ushort_t;
typedef unsigned int uint_t;

__device__ inline ushort_t f2bf(float x) {
  uint_t u = __float_as_uint(x);
  uint_t r = (u + 0x7fffu + ((u >> 16) & 1u)) >> 16;   // RNE
  return (ushort_t)r;
}
__device__ inline float bf2f(ushort_t b) { return __uint_as_float((uint_t)b << 16); }
__device__ inline uint_t pack2bf(float a, float b) {
  return (uint_t)f2bf(a) | ((uint_t)f2bf(b) << 16);
}
__device__ inline float bflo(uint_t u) { return __uint_as_float(u << 16); }
__device__ inline float bfhi(uint_t u) { return __uint_as_float(u & 0xffff0000u); }

// async global->LDS, 16 B per lane (global_load_lds_dwordx4)
__device__ inline void async_cp16(const ushort_t* g, ushort_t* l) {
  __builtin_amdgcn_global_load_lds((const __attribute__((address_space(1))) void*)g,
                                   (__attribute__((address_space(3))) void*)l, 16, 0, 0);
}

// ---------------- prep kernels ----------------
__global__ void hist_kernel(const int* __restrict__ src, const int* __restrict__ dst,
                            int* __restrict__ deg_out, int* __restrict__ deg_in) {
  int e = blockIdx.x * 256 + threadIdx.x;
  if (e < N_EDGES) {
    atomicAdd(&deg_out[src[e]], 1);
    atomicAdd(&deg_in[dst[e]], 1);
  }
}

__global__ void norm_kernel(const int* __restrict__ deg_out, const int* __restrict__ deg_in,
                            float* __restrict__ norm_out, float* __restrict__ norm_in) {
  int v = blockIdx.x * 256 + threadIdx.x;
  if (v < N_NODES) {
    norm_out[v] = rsqrtf((float)max(deg_out[v], 1));
    norm_in[v]  = rsqrtf((float)max(deg_in[v], 1));
  }
}

__global__ void scan1_kernel(const int* __restrict__ deg_in, int* __restrict__ bsums) {
  __shared__ int sred[256];
  int t0 = blockIdx.x * 1024 + threadIdx.x * 4;
  int s = 0;
#pragma unroll
  for (int i = 0; i < 4; i++) { int v = t0 + i; s += (v < N_NODES) ? deg_in[v] : 0; }
  sred[threadIdx.x] = s; __syncthreads();
  for (int off = 128; off > 0; off >>= 1) {
    if (threadIdx.x < off) sred[threadIdx.x] += sred[threadIdx.x + off];
    __syncthreads();
  }
  if (threadIdx.x == 0) bsums[blockIdx.x] = sred[0];
}

__global__ void scan2_kernel(const int* __restrict__ bsums, int* __restrict__ bofs,
                             int* __restrict__ row_ptr, int nb) {
  if (threadIdx.x == 0 && blockIdx.x == 0) {
    int run = 0;
    for (int i = 0; i < nb; i++) { bofs[i] = run; run += bsums[i]; }
    row_ptr[N_NODES] = run;
  }
}

__global__ void scan3_kernel(const int* __restrict__ deg_in, const int* __restrict__ bofs,
                             int* __restrict__ row_ptr) {
  __shared__ int ssc[256];
  int t0 = blockIdx.x * 1024 + threadIdx.x * 4;
  int v4[4]; int s = 0;
#pragma unroll
  for (int i = 0; i < 4; i++) { int v = t0 + i; v4[i] = (v < N_NODES) ? deg_in[v] : 0; s += v4[i]; }
  ssc[threadIdx.x] = s; __syncthreads();
  for (int off = 1; off < 256; off <<= 1) {
    int t = (threadIdx.x >= off) ? ssc[threadIdx.x - off] : 0;
    __syncthreads();
    ssc[threadIdx.x] += t;
    __syncthreads();
  }
  int ex = ssc[threadIdx.x] - s + bofs[blockIdx.x];
#pragma unroll
  for (int i = 0; i < 4; i++) {
    int v = t0 + i;
    if (v < N_NODES) { row_ptr[v] = ex; ex += v4[i]; }
  }
}

__global__ void csr_fill_kernel(const int* __restrict__ src, const int* __restrict__ dst,
                                const int* __restrict__ row_ptr, int* __restrict__ fill,
                                int* __restrict__ csr) {
  int e = blockIdx.x * 256 + threadIdx.x;
  if (e < N_EDGES) {
    int d = dst[e];
    int slot = atomicAdd(&fill[d], 1);
    csr[row_ptr[d] + slot] = src[e];
  }
}

// ---------- W swizzle into MFMA B-fragment order ----------
__global__ void wtrans_kernel(const float* __restrict__ W_emb, const float* __restrict__ Ws,
                              ushort_t* __restrict__ Wb, ushort_t* __restrict__ Wh) {
  int idx = blockIdx.x * 256 + threadIdx.x;
  if (idx >= 5 * 5 * 10 * 64 * 8) return;
  int j = idx & 7;
  int t = idx >> 3;
  int lane = t & 63; t >>= 6;
  int nt = t % 10; t /= 10;
  int kc = t % 5;
  int m = t / 5;
  const float* W = (m == 0) ? W_emb : Ws + (size_t)(m - 1) * DIM * DIM;
  int k = kc * 32 + (lane >> 4) * 8 + j;
  int n = nt * 16 + (lane & 15);
  float w = (k < DIM && n < DIM) ? W[k * DIM + n] : 0.f;
  ushort_t hi = f2bf(w);
  float lo = w - bf2f(hi);
  size_t base = (size_t)((((m * 5 + kc) * 10 + nt) * 2) * 64 + lane) * 8 + j;
  Wb[base] = hi;
  Wb[base + 512] = f2bf(lo);
  Wh[(size_t)(((m * 5 + kc) * 10 + nt) * 64 + lane) * 8 + j] = hi;
}

// in-register A-fragment from fp32 row
__device__ inline bf16x8 make_frag(const float* __restrict__ nf, int row, int kc, int quad) {
  union { bf16x8 v; ushort_t u[8]; } r;
  const float* p = nf + (size_t)row * DIM + kc * 32 + quad * 8;
  int c0 = kc * 32 + quad * 8;
  if (c0 + 8 <= DIM) {
    float2 q0 = *(const float2*)(p);
    float2 q1 = *(const float2*)(p + 2);
    float2 q2 = *(const float2*)(p + 4);
    float2 q3 = *(const float2*)(p + 6);
    r.u[0] = f2bf(q0.x); r.u[1] = f2bf(q0.y); r.u[2] = f2bf(q1.x); r.u[3] = f2bf(q1.y);
    r.u[4] = f2bf(q2.x); r.u[5] = f2bf(q2.y); r.u[6] = f2bf(q3.x); r.u[7] = f2bf(q3.y);
  } else {
#pragma unroll
    for (int j = 0; j < 8; j++) r.u[j] = (c0 + j < DIM) ? f2bf(p[j]) : (ushort_t)0;
  }
  return r.v;
}

// ------------- embedding GEMM (unchanged from R9) -------------
__global__ __launch_bounds__(256, 3) void gemm_embed_kernel(
    const float* __restrict__ nf, const ushort_t* __restrict__ Wb,
    const float* __restrict__ bias, const float* __restrict__ norm_out,
    float* __restrict__ h, ushort_t* __restrict__ hb) {
  __shared__ __align__(16) ushort_t sB[2][10240];
  int wave = threadIdx.x >> 6, lane = threadIdx.x & 63;
  int quad = lane >> 4, l16 = lane & 15;
  int m0 = blockIdx.x * 128 + wave * 32;
  int ra = min(m0 + l16, N_NODES - 1);
  int rb = min(m0 + 16 + l16, N_NODES - 1);

  auto stage = [&](int buf, int kc) {
    const ushort_t* wsrc = Wb + (size_t)kc * 10240 + threadIdx.x * 8;
    ushort_t* ldst = &sB[buf][threadIdx.x * 8];
#pragma unroll
    for (int p = 0; p < 5; p++) async_cp16(wsrc + p * 2048, ldst + p * 2048);
  };

  stage(0, 0);
  __syncthreads();

  floatx4 acc[2][10];
#pragma unroll
  for (int s = 0; s < 2; s++)
#pragma unroll
    for (int nt = 0; nt < 10; nt++) acc[s][nt] = (floatx4){0.f, 0.f, 0.f, 0.f};

#pragma unroll
  for (int kc = 0; kc < 5; kc++) {
    int buf = kc & 1;
    if (kc < 4) stage(buf ^ 1, kc + 1);
    bf16x8 a0 = make_frag(nf, ra, kc, quad);
    bf16x8 a1 = make_frag(nf, rb, kc, quad);
    const ushort_t* bp = &sB[buf][lane * 8];
#pragma unroll
    for (int nt = 0; nt < 10; nt++) {
      bf16x8 bh = *(const bf16x8*)(bp + (nt * 2) * 512);
      bf16x8 bl = *(const bf16x8*)(bp + (nt * 2 + 1) * 512);
      acc[0][nt] = __builtin_amdgcn_mfma_f32_16x16x32_bf16(a0, bh, acc[0][nt], 0, 0, 0);
      acc[1][nt] = __builtin_amdgcn_mfma_f32_16x16x32_bf16(a1, bh, acc[1][nt], 0, 0, 0);
      acc[0][nt] = __builtin_amdgcn_mfma_f32_16x16x32_bf16(a0, bl, acc[0][nt], 0, 0, 0);
      acc[1][nt] = __builtin_amdgcn_mfma_f32_16x16x32_bf16(a1, bl, acc[1][nt], 0, 0, 0);
    }
    __syncthreads();
  }

  float no[2][4];
#pragma unroll
  for (int s = 0; s < 2; s++)
#pragma unroll
    for (int r = 0; r < 4; r++) no[s][r] = norm_out[min(m0 + s * 16 + quad * 4 + r, N_NODES - 1)];

  float* sF = (float*)&sB[0][0];
#pragma unroll
  for (int nt = 0; nt < 5; nt++) {
    int c = nt * 16 + l16;
    float b = bias[c];
#pragma unroll
    for (int s = 0; s < 2; s++)
#pragma unroll
      for (int r = 0; r < 4; r++)
        sF[(wave * 32 + s * 16 + quad * 4 + r) * 80 + c] = acc[s][nt][r] + b;
  }
  __syncthreads();
#pragma unroll
  for (int i = 0; i < 10; i++) {
    int n = threadIdx.x + i * 256;
    int row = n / 20, ch = n - row * 20;
    int grow = blockIdx.x * 128 + row;
    if (grow < N_NODES)
      *((uint4*)(h + (size_t)grow * HPAD) + ch) = ((const uint4*)(sF + row * 80))[ch];
  }
  __syncthreads();
#pragma unroll
  for (int nt = 5; nt < 10; nt++) {
    int c = nt * 16 + l16;
    float b = (c < DIM) ? bias[c] : 0.f;
#pragma unroll
    for (int s = 0; s < 2; s++)
#pragma unroll
      for (int r = 0; r < 4; r++)
        sF[(wave * 32 + s * 16 + quad * 4 + r) * 80 + (c - 80)] = acc[s][nt][r] + b;
  }
  __syncthreads();
#pragma unroll
  for (int i = 0; i < 10; i++) {
    int n = threadIdx.x + i * 256;
    int row = n / 20, ch = n - row * 20;
    int grow = blockIdx.x * 128 + row;
    if (grow < N_NODES)
      *((uint4*)(h + (size_t)grow * HPAD + 80) + ch) = ((const uint4*)(sF + row * 80))[ch];
  }
  __syncthreads();
  ushort_t* sC = &sB[0][0];
#pragma unroll
  for (int nt = 0; nt < 10; nt++) {
    int c = nt * 16 + l16;
    float b = (c < DIM) ? bias[c] : 0.f;
#pragma unroll
    for (int s = 0; s < 2; s++)
#pragma unroll
      for (int r = 0; r < 4; r++)
        sC[(wave * 32 + s * 16 + quad * 4 + r) * 160 + c] = f2bf((acc[s][nt][r] + b) * no[s][r]);
  }
  __syncthreads();
#pragma unroll
  for (int i = 0; i < 10; i++) {
    int n = threadIdx.x + i * 256;
    int row = n / 20, ch = n - row * 20;
    int grow = blockIdx.x * 128 + row;
    if (grow < N_NODES)
      *((uint4*)(hb + (size_t)grow * APAD) + ch) = ((const uint4*)(sC + row * 160))[ch];
  }
}

// ---------- fused LAYER GEMM + BN + ReLU + residual (+graph-sum for LAST) ----------
// Phase A: MFMA K-loop + column stats -> global (device atomics).
// Grid barrier (all 782 blocks co-resident: __launch_bounds__(256,4) -> 1024 slots).
// Phase B: BN coeffs from stats; 4 quarter-passes stage h through LDS, apply, write back.
template <bool LAST>
__global__ __launch_bounds__(256, 4) void gemm_bn_kernel(
    const ushort_t* __restrict__ Abf, const ushort_t* __restrict__ Wh,
    const float* __restrict__ bias, const float* __restrict__ snorm,
    float* __restrict__ stats, const float* __restrict__ gamma,
    const float* __restrict__ beta, const float* __restrict__ norm_out,
    float* __restrict__ h, ushort_t* __restrict__ hb,
    const int* __restrict__ gids, float* __restrict__ hgp, int* __restrict__ gbar) {
  __shared__ __align__(16) ushort_t sB[2][5120];   // K staging; reused as sH (32x160 f32)
  __shared__ __align__(16) ushort_t sHB[5120];     // 32x160 bf16 hb staging
  __shared__ float sred[2 * DIM];
  __shared__ float sbn[2 * DIM];
  int wave = threadIdx.x >> 6, lane = threadIdx.x & 63;
  int quad = lane >> 4, l16 = lane & 15;
  int m0 = blockIdx.x * 128 + wave * 32;
  int ra = min(m0 + l16, N_NODES - 1);
  int rb = min(m0 + 16 + l16, N_NODES - 1);
  const ushort_t* ap0 = Abf + (size_t)ra * APAD + quad * 8;
  const ushort_t* ap1 = Abf + (size_t)rb * APAD + quad * 8;

  auto stage = [&](int buf, int kc) {
    const ushort_t* wsrc = Wh + (size_t)kc * 5120;
    ushort_t* ldst = &sB[buf][0];
    async_cp16(wsrc + threadIdx.x * 8, ldst + threadIdx.x * 8);
    async_cp16(wsrc + (threadIdx.x + 256) * 8, ldst + (threadIdx.x + 256) * 8);
    if (threadIdx.x < 128)
      async_cp16(wsrc + (threadIdx.x + 512) * 8, ldst + (threadIdx.x + 512) * 8);
  };

  stage(0, 0);
  bf16x8 a0[5], a1[5];
#pragma unroll
  for (int kc = 0; kc < 5; kc++) {
    a0[kc] = *(const bf16x8*)(ap0 + kc * 32);
    a1[kc] = *(const bf16x8*)(ap1 + kc * 32);
  }
  for (int i = threadIdx.x; i < 2 * DIM; i += 256) sred[i] = 0.f;
  __syncthreads();

  floatx4 acc[2][10];
#pragma unroll
  for (int s = 0; s < 2; s++)
#pragma unroll
    for (int nt = 0; nt < 10; nt++) acc[s][nt] = (floatx4){0.f, 0.f, 0.f, 0.f};

  for (int kc = 0; kc < 5; kc++) {
    int buf = kc & 1;
    if (kc < 4) stage(buf ^ 1, kc + 1);
    const ushort_t* bp = &sB[buf][lane * 8];
#pragma unroll
    for (int nt = 0; nt < 10; nt++) {
      bf16x8 bh = *(const bf16x8*)(bp + nt * 512);
      acc[0][nt] = __builtin_amdgcn_mfma_f32_16x16x32_bf16(a0[kc], bh, acc[0][nt], 0, 0, 0);
      acc[1][nt] = __builtin_amdgcn_mfma_f32_16x16x32_bf16(a1[kc], bh, acc[1][nt], 0, 0, 0);
    }
    __syncthreads();
  }

  // per-wave row scalars
  float sn[2][4], no[2][4];
#pragma unroll
  for (int s = 0; s < 2; s++)
#pragma unroll
    for (int r = 0; r < 4; r++) {
      int row = min(m0 + s * 16 + quad * 4 + r, N_NODES - 1);
      sn[s][r] = snorm[row];
      no[s][r] = LAST ? 0.f : norm_out[row];
    }
  float bv[10];
#pragma unroll
  for (int nt = 0; nt < 10; nt++) {
    int c = nt * 16 + l16;
    bv[nt] = (c < DIM) ? bias[c] : 0.f;
  }

  // stats
#pragma unroll
  for (int nt = 0; nt < 10; nt++) {
    int c = nt * 16 + l16;
    if (c < DIM) {
      float ssum = 0.f, ssq = 0.f;
#pragma unroll
      for (int s = 0; s < 2; s++)
#pragma unroll
        for (int r = 0; r < 4; r++) {
          if (m0 + s * 16 + quad * 4 + r < N_NODES) {
            float val = (acc[s][nt][r] + bv[nt]) * sn[s][r];
            ssum += val; ssq += val * val;
          }
        }
      ssum += __shfl_xor(ssum, 16, 64); ssum += __shfl_xor(ssum, 32, 64);
      ssq  += __shfl_xor(ssq, 16, 64);  ssq  += __shfl_xor(ssq, 32, 64);
      if (quad == 0) {
        atomicAdd(&sred[c], ssum);
        atomicAdd(&sred[DIM + c], ssq);
      }
    }
  }
  __syncthreads();
  {
    float* stp = stats + (blockIdx.x & (ST_PART - 1)) * 2 * DIM;
    for (int i = threadIdx.x; i < 2 * DIM; i += 256) atomicAdd(&stp[i], sred[i]);
  }

  // ---- grid barrier ----
  __syncthreads();   // drains vmcnt: all this block's stat atomics complete
  if (threadIdx.x == 0) {
    __threadfence();
    atomicAdd(gbar, 1);
    while (__hip_atomic_load(gbar, __ATOMIC_ACQUIRE, __HIP_MEMORY_SCOPE_AGENT) < GRID_GB)
      __builtin_amdgcn_s_sleep(8);
  }
  __syncthreads();

  // ---- BN coefficients ----
  for (int c = threadIdx.x; c < DIM; c += 256) {
    float su = 0.f, sq = 0.f;
#pragma unroll
    for (int p = 0; p < ST_PART; p++) {
      su += __hip_atomic_load(&stats[p * 2 * DIM + c], __ATOMIC_RELAXED, __HIP_MEMORY_SCOPE_AGENT);
      sq += __hip_atomic_load(&stats[p * 2 * DIM + DIM + c], __ATOMIC_RELAXED, __HIP_MEMORY_SCOPE_AGENT);
    }
    float mu = su * (1.f / N_NODES);
    float var = sq * (1.f / N_NODES) - mu * mu;
    float sc = gamma[c] * rsqrtf(var + BN_EPS);
    sbn[c] = sc;
    sbn[DIM + c] = beta[c] - mu * sc;
  }
  __syncthreads();

  // ---- Phase B: 4 quarter-passes of 32 rows ----
  float* sH = (float*)&sB[0][0];          // 32 x 160 fp32 = 20 KB
  uint4* sH4 = (uint4*)sH;
  for (int p = 0; p < 4; p++) {
    int pr0 = blockIdx.x * 128 + p * 32;
    const uint4* hg4 = (const uint4*)(h + (size_t)pr0 * HPAD);
#pragma unroll
    for (int i = 0; i < 5; i++) {
      int n = threadIdx.x + i * 256;      // < 1280 = 32 rows * 40 uint4
      sH4[n] = (pr0 + n / 40 < N_NODES) ? hg4[n] : make_uint4(0, 0, 0, 0);
    }
    __syncthreads();
    if (wave == p) {
#pragma unroll
      for (int nt = 0; nt < 10; nt++) {
        int c = nt * 16 + l16;
#pragma unroll
        for (int s = 0; s < 2; s++)
#pragma unroll
          for (int r = 0; r < 4; r++) {
            int gi = (s * 16 + quad * 4 + r) * 160 + c;
            if (c < DIM) {
              float val = (acc[s][nt][r] + bv[nt]) * sn[s][r];
              float x = fmaxf(fmaf(val, sbn[c], sbn[DIM + c]), 0.f);
              float hnew = sH[gi] + x;
              sH[gi] = hnew;
              if (!LAST) ((ushort_t*)sHB)[gi] = f2bf(hnew * no[s][r]);
            } else {
              if (!LAST) ((ushort_t*)sHB)[gi] = 0;
            }
          }
      }
    }
    __syncthreads();
    if (!LAST) {
      uint4* hw4 = (uint4*)(h + (size_t)pr0 * HPAD);
#pragma unroll
      for (int i = 0; i < 5; i++) {
        int n = threadIdx.x + i * 256;
        if (pr0 + n / 40 < N_NODES) hw4[n] = sH4[n];
      }
      uint4* hb4 = (uint4*)(hb + (size_t)pr0 * APAD);
#pragma unroll
      for (int i = 0; i < 3; i++) {
        int n = threadIdx.x + i * 256;    // 640 = 32 rows * 20 uint4
        if (n < 640 && pr0 + n / 20 < N_NODES) hb4[n] = ((const uint4*)sHB)[n];
      }
    } else {
      int t = threadIdx.x;
      if (t <= DIM && pr0 < N_NODES) {
        int part = blockIdx.x & (GS_PART - 1);
        float accv = 0.f;
        int g_prev = gids[pr0];
        for (int rr = 0; rr < 32; rr++) {
          int r = pr0 + rr;
          if (r >= N_NODES) break;
          int g = gids[r];
          if (g != g_prev) {
            atomicAdd(&hgp[(size_t)(part * N_GRAPHS + g_prev) * GS_STRIDE + t], accv);
            accv = 0.f; g_prev = g;
          }
          accv += (t < DIM) ? sH[rr * 160 + t] : 1.f;
        }
        atomicAdd(&hgp[(size_t)(part * N_GRAPHS + g_prev) * GS_STRIDE + t], accv);
      }
    }
    __syncthreads();
  }
}

// ------- aggregation: one wave per destination node, bf16 gather (pre-scaled hb) -------
__global__ __launch_bounds__(256) void agg_kernel(
    const ushort_t* __restrict__ hb, const int* __restrict__ row_ptr,
    const int* __restrict__ csr, const float* __restrict__ norm_in,
    ushort_t* __restrict__ xb) {
  int wid = threadIdx.x >> 6, lane = threadIdx.x & 63;
  int v = blockIdx.x * 4 + wid;
  if (v >= N_NODES) return;
  int e0 = row_ptr[v], e1 = row_ptr[v + 1];
  bool act = lane < 40;
  int col8 = lane * 4;
  float a0 = 0.f, a1 = 0.f, a2 = 0.f, a3 = 0.f;
  float b0 = 0.f, b1 = 0.f, b2 = 0.f, b3 = 0.f;
  int e = e0;
  for (; e + 1 < e1; e += 2) {
    int s0 = csr[e], s1 = csr[e + 1];
    if (act) {
      uint2 u0 = *(const uint2*)(hb + (size_t)s0 * APAD + col8);
      uint2 u1 = *(const uint2*)(hb + (size_t)s1 * APAD + col8);
      a0 += bflo(u0.x); a1 += bfhi(u0.x); a2 += bflo(u0.y); a3 += bfhi(u0.y);
      b0 += bflo(u1.x); b1 += bfhi(u1.x); b2 += bflo(u1.y); b3 += bfhi(u1.y);
    }
  }
  if (e < e1) {
    int s0 = csr[e];
    if (act) {
      uint2 u0 = *(const uint2*)(hb + (size_t)s0 * APAD + col8);
      a0 += bflo(u0.x); a1 += bfhi(u0.x); a2 += bflo(u0.y); a3 += bfhi(u0.y);
    }
  }
  if (act) {
    float ni = norm_in[v];
    uint2 o;
    o.x = pack2bf((a0 + b0) * ni, (a1 + b1) * ni);
    o.y = pack2bf((a2 + b2) * ni, (a3 + b3) * ni);
    *(uint2*)((uint_t*)(xb + (size_t)v * APAD) + lane * 2) = o;
  }
}

// ---------------- fused mean + MLP readout: one block per graph ----------------
__global__ __launch_bounds__(256) void mlp_kernel(
    const float* __restrict__ hgp,
    const float* __restrict__ W1, const float* __restrict__ b1,
    const float* __restrict__ W2, const float* __restrict__ b2,
    const float* __restrict__ W3, const float* __restrict__ b3,
    float* __restrict__ out) {
  __shared__ float hrow[DIM];
  __shared__ float x1[73];
  __shared__ float x2[36];
  int g = blockIdx.x;
  int t = threadIdx.x;
  if (t < DIM) {
    float s = 0.f, cnt = 0.f;
#pragma unroll
    for (int p = 0; p < GS_PART; p++) {
      const float* row = hgp + (size_t)(p * N_GRAPHS + g) * GS_STRIDE;
      s += row[t];
      cnt += row[DIM];
    }
    hrow[t] = s / cnt;
  }
  __syncthreads();
  if (t < 73) {
    float s = b1[t];
    for (int k = 0; k < DIM; k++) s = fmaf(hrow[k], W1[k * 73 + t], s);
    x1[t] = s > 0.f ? s : 0.f;
  }
  __syncthreads();
  if (t < 36) {
    float s = b2[t];
    for (int k = 0; k < 73; k++) s = fmaf(x1[k], W2[k * 36 + t], s);
    x2[t] = s > 0.f ? s : 0.f;
  }
  __syncthreads();
  if (t < 10) {
    float s = b3[t];
    for (int k = 0; k < 36; k++) s = fmaf(x2[k], W3[k * 10 + t], s);
    out[g * 10 + t] = s;
  }
}

extern "C" void kernel_launch(void* const* d_in, const int* in_sizes, int n_in,
                              void* d_out, int out_size, void* d_ws, size_t ws_size,
                              hipStream_t stream) {
  const float* nodes_feat = (const float*)d_in[0];
  const float* snorm  = (const float*)d_in[1];
  const float* W_emb  = (const float*)d_in[2];
  const float* b_emb  = (const float*)d_in[3];
  const float* Ws     = (const float*)d_in[4];
  const float* bs     = (const float*)d_in[5];
  const float* gammas = (const float*)d_in[6];
  const float* betas  = (const float*)d_in[7];
  const float* W1 = (const float*)d_in[8];
  const float* b1 = (const float*)d_in[9];
  const float* W2 = (const float*)d_in[10];
  const float* b2 = (const float*)d_in[11];
  const float* W3 = (const float*)d_in[12];
  const float* b3 = (const float*)d_in[13];
  const int* src  = (const int*)d_in[14];
  const int* dst  = (const int*)d_in[15];
  const int* gids = (const int*)d_in[16];
  float* out = (float*)d_out;

  const int GB = GRID_GB;   // 782 blocks, 128 rows each

  char* base = (char*)d_ws;
  size_t off = 0;
  auto alloc = [&](size_t bytes) { void* p = base + off; off += (bytes + 255) & ~size_t(255); return p; };
  float* h    = (float*)alloc((size_t)N_NODES * HPAD * 4);
  ushort_t* xb = (ushort_t*)alloc((size_t)N_NODES * APAD * 2);    // bf16 GEMM input
  ushort_t* hb = (ushort_t*)alloc((size_t)N_NODES * APAD * 2);    // bf16 h * norm_out
  char* zstart = base + off;
  int* deg_out = (int*)alloc(N_NODES * 4);
  int* deg_in  = (int*)alloc(N_NODES * 4);
  int* fill    = (int*)alloc(N_NODES * 4);
  float* stats = (float*)alloc(4 * ST_PART * 2 * DIM * 4);  // per layer: ST_PART x [sum,sumsq]
  float* hgp   = (float*)alloc((size_t)GS_PART * N_GRAPHS * GS_STRIDE * 4);
  int* gbar    = (int*)alloc(4 * 4);                        // grid-barrier counters
  size_t zbytes = (size_t)((base + off) - zstart);
  int* row_ptr = (int*)alloc((N_NODES + 1) * 4);
  float* norm_out = (float*)alloc(N_NODES * 4);
  float* norm_in  = (float*)alloc(N_NODES * 4);
  int* csr   = (int*)alloc((size_t)N_EDGES * 4);
  int* bsums = (int*)alloc(128 * 4);
  int* bofs  = (int*)alloc(128 * 4);
  ushort_t* Wb = (ushort_t*)alloc((size_t)5 * 5 * 10 * 2 * 64 * 8 * 2);  // split hi/lo
  ushort_t* Wh = (ushort_t*)alloc((size_t)5 * 5 * 10 * 64 * 8 * 2);      // hi only

  hipMemsetAsync(zstart, 0, zbytes, stream);

  hist_kernel<<<(N_EDGES + 255) / 256, 256, 0, stream>>>(src, dst, deg_out, deg_in);
  norm_kernel<<<(N_NODES + 255) / 256, 256, 0, stream>>>(deg_out, deg_in, norm_out, norm_in);
  int nb = (N_NODES + 1023) / 1024;
  scan1_kernel<<<nb, 256, 0, stream>>>(deg_in, bsums);
  scan2_kernel<<<1, 64, 0, stream>>>(bsums, bofs, row_ptr, nb);
  scan3_kernel<<<nb, 256, 0, stream>>>(deg_in, bofs, row_ptr);
  csr_fill_kernel<<<(N_EDGES + 255) / 256, 256, 0, stream>>>(src, dst, row_ptr, fill, csr);
  wtrans_kernel<<<(5 * 5 * 10 * 64 * 8 + 255) / 256, 256, 0, stream>>>(W_emb, Ws, Wb, Wh);

  const size_t WHM = (size_t)5 * 10 * 64 * 8;      // Wh elems per matrix (25600)

  gemm_embed_kernel<<<GB, 256, 0, stream>>>(nodes_feat, Wb, b_emb, norm_out, h, hb);

  for (int l = 0; l < 4; l++) {
    float* st = stats + (size_t)l * ST_PART * 2 * DIM;
    agg_kernel<<<(N_NODES + 3) / 4, 256, 0, stream>>>(hb, row_ptr, csr, norm_in, xb);
    if (l < 3) {
      gemm_bn_kernel<false><<<GB, 256, 0, stream>>>(
          xb, Wh + (size_t)(l + 1) * WHM, bs + l * DIM, snorm, st,
          gammas + l * DIM, betas + l * DIM, norm_out, h, hb, nullptr, nullptr, gbar + l);
    } else {
      gemm_bn_kernel<true><<<GB, 256, 0, stream>>>(
          xb, Wh + (size_t)(l + 1) * WHM, bs + l * DIM, snorm, st,
          gammas + l * DIM, betas + l * DIM, norm_out, h, nullptr, gids, hgp, gbar + l);
    }
  }

  mlp_kernel<<<N_GRAPHS, 256, 0, stream>>>(hgp, W1, b1, W2, b2, W3, b3, out);
}

// Round 11
// 708.365 us; speedup vs baseline: 1.5416x; 1.5416x over previous
//
#include <hip/hip_runtime.h>

#define N_NODES 100000
#define N_EDGES 500000
#define N_GRAPHS 100
#define DIM 146
#define APAD 160        // padded bf16 row stride (16B-aligned, 5 k-chunks of 32)
#define HPAD 160        // padded fp32 h row stride (640 B, 16B-aligned)
#define TPW 160         // tmp bf16 row stride (ushorts)
#define BN_EPS 1e-5f
#define GS_PART 8
#define GS_STRIDE 147   // 146 cols + 1 count slot
#define ST_PART 4       // stat-atomic partitions

typedef __bf16 bf16x8 __attribute__((ext_vector_type(8)));
typedef float floatx4 __attribute__((ext_vector_type(4)));
typedef unsigned short ushort_t;
typedef unsigned int uint_t;

__device__ inline ushort_t f2bf(float x) {
  uint_t u = __float_as_uint(x);
  uint_t r = (u + 0x7fffu + ((u >> 16) & 1u)) >> 16;   // RNE
  return (ushort_t)r;
}
__device__ inline float bf2f(ushort_t b) { return __uint_as_float((uint_t)b << 16); }
__device__ inline uint_t pack2bf(float a, float b) {
  return (uint_t)f2bf(a) | ((uint_t)f2bf(b) << 16);
}
__device__ inline float bflo(uint_t u) { return __uint_as_float(u << 16); }
__device__ inline float bfhi(uint_t u) { return __uint_as_float(u & 0xffff0000u); }

// async global->LDS, 16 B per lane (global_load_lds_dwordx4)
__device__ inline void async_cp16(const ushort_t* g, ushort_t* l) {
  __builtin_amdgcn_global_load_lds((const __attribute__((address_space(1))) void*)g,
                                   (__attribute__((address_space(3))) void*)l, 16, 0, 0);
}

// ---------------- prep kernels ----------------
__global__ void hist_kernel(const int* __restrict__ src, const int* __restrict__ dst,
                            int* __restrict__ deg_out, int* __restrict__ deg_in) {
  int e = blockIdx.x * 256 + threadIdx.x;
  if (e < N_EDGES) {
    atomicAdd(&deg_out[src[e]], 1);
    atomicAdd(&deg_in[dst[e]], 1);
  }
}

__global__ void norm_kernel(const int* __restrict__ deg_out, const int* __restrict__ deg_in,
                            float* __restrict__ norm_out, float* __restrict__ norm_in) {
  int v = blockIdx.x * 256 + threadIdx.x;
  if (v < N_NODES) {
    norm_out[v] = rsqrtf((float)max(deg_out[v], 1));
    norm_in[v]  = rsqrtf((float)max(deg_in[v], 1));
  }
}

__global__ void scan1_kernel(const int* __restrict__ deg_in, int* __restrict__ bsums) {
  __shared__ int sred[256];
  int t0 = blockIdx.x * 1024 + threadIdx.x * 4;
  int s = 0;
#pragma unroll
  for (int i = 0; i < 4; i++) { int v = t0 + i; s += (v < N_NODES) ? deg_in[v] : 0; }
  sred[threadIdx.x] = s; __syncthreads();
  for (int off = 128; off > 0; off >>= 1) {
    if (threadIdx.x < off) sred[threadIdx.x] += sred[threadIdx.x + off];
    __syncthreads();
  }
  if (threadIdx.x == 0) bsums[blockIdx.x] = sred[0];
}

__global__ void scan2_kernel(const int* __restrict__ bsums, int* __restrict__ bofs,
                             int* __restrict__ row_ptr, int nb) {
  if (threadIdx.x == 0 && blockIdx.x == 0) {
    int run = 0;
    for (int i = 0; i < nb; i++) { bofs[i] = run; run += bsums[i]; }
    row_ptr[N_NODES] = run;
  }
}

__global__ void scan3_kernel(const int* __restrict__ deg_in, const int* __restrict__ bofs,
                             int* __restrict__ row_ptr) {
  __shared__ int ssc[256];
  int t0 = blockIdx.x * 1024 + threadIdx.x * 4;
  int v4[4]; int s = 0;
#pragma unroll
  for (int i = 0; i < 4; i++) { int v = t0 + i; v4[i] = (v < N_NODES) ? deg_in[v] : 0; s += v4[i]; }
  ssc[threadIdx.x] = s; __syncthreads();
  for (int off = 1; off < 256; off <<= 1) {
    int t = (threadIdx.x >= off) ? ssc[threadIdx.x - off] : 0;
    __syncthreads();
    ssc[threadIdx.x] += t;
    __syncthreads();
  }
  int ex = ssc[threadIdx.x] - s + bofs[blockIdx.x];
#pragma unroll
  for (int i = 0; i < 4; i++) {
    int v = t0 + i;
    if (v < N_NODES) { row_ptr[v] = ex; ex += v4[i]; }
  }
}

__global__ void csr_fill_kernel(const int* __restrict__ src, const int* __restrict__ dst,
                                const int* __restrict__ row_ptr, int* __restrict__ fill,
                                int* __restrict__ csr) {
  int e = blockIdx.x * 256 + threadIdx.x;
  if (e < N_EDGES) {
    int d = dst[e];
    int slot = atomicAdd(&fill[d], 1);
    csr[row_ptr[d] + slot] = src[e];
  }
}

// ---------- W swizzle into MFMA B-fragment order ----------
// Wb: hi/lo split, per-(m,kc) 20 KB slice (embed kernel).
// Wh: hi only,     per-(m,kc) 10 KB slice (layer kernels).
__global__ void wtrans_kernel(const float* __restrict__ W_emb, const float* __restrict__ Ws,
                              ushort_t* __restrict__ Wb, ushort_t* __restrict__ Wh) {
  int idx = blockIdx.x * 256 + threadIdx.x;
  if (idx >= 5 * 5 * 10 * 64 * 8) return;
  int j = idx & 7;
  int t = idx >> 3;
  int lane = t & 63; t >>= 6;
  int nt = t % 10; t /= 10;
  int kc = t % 5;
  int m = t / 5;
  const float* W = (m == 0) ? W_emb : Ws + (size_t)(m - 1) * DIM * DIM;
  int k = kc * 32 + (lane >> 4) * 8 + j;
  int n = nt * 16 + (lane & 15);
  float w = (k < DIM && n < DIM) ? W[k * DIM + n] : 0.f;
  ushort_t hi = f2bf(w);
  float lo = w - bf2f(hi);
  size_t base = (size_t)((((m * 5 + kc) * 10 + nt) * 2) * 64 + lane) * 8 + j;
  Wb[base] = hi;
  Wb[base + 512] = f2bf(lo);
  Wh[(size_t)(((m * 5 + kc) * 10 + nt) * 64 + lane) * 8 + j] = hi;
}

// in-register A-fragment from fp32 row (RNE pack, identical to nf2bf numerics)
__device__ inline bf16x8 make_frag(const float* __restrict__ nf, int row, int kc, int quad) {
  union { bf16x8 v; ushort_t u[8]; } r;
  const float* p = nf + (size_t)row * DIM + kc * 32 + quad * 8;
  int c0 = kc * 32 + quad * 8;
  if (c0 + 8 <= DIM) {
    float2 q0 = *(const float2*)(p);
    float2 q1 = *(const float2*)(p + 2);
    float2 q2 = *(const float2*)(p + 4);
    float2 q3 = *(const float2*)(p + 6);
    r.u[0] = f2bf(q0.x); r.u[1] = f2bf(q0.y); r.u[2] = f2bf(q1.x); r.u[3] = f2bf(q1.y);
    r.u[4] = f2bf(q2.x); r.u[5] = f2bf(q2.y); r.u[6] = f2bf(q3.x); r.u[7] = f2bf(q3.y);
  } else {
#pragma unroll
    for (int j = 0; j < 8; j++) r.u[j] = (c0 + j < DIM) ? f2bf(p[j]) : (ushort_t)0;
  }
  return r.v;
}

// ------------- embedding GEMM: fp32 A direct, split-precision W, LDS-staged epilogue -------------
__global__ __launch_bounds__(256, 3) void gemm_embed_kernel(
    const float* __restrict__ nf, const ushort_t* __restrict__ Wb,
    const float* __restrict__ bias, const float* __restrict__ norm_out,
    float* __restrict__ h, ushort_t* __restrict__ hb) {
  __shared__ __align__(16) ushort_t sB[2][10240];   // 2 x 20 KB B slices; epilogue reuse
  int wave = threadIdx.x >> 6, lane = threadIdx.x & 63;
  int quad = lane >> 4, l16 = lane & 15;
  int m0 = blockIdx.x * 128 + wave * 32;
  int ra = min(m0 + l16, N_NODES - 1);
  int rb = min(m0 + 16 + l16, N_NODES - 1);

  auto stage = [&](int buf, int kc) {
    const ushort_t* wsrc = Wb + (size_t)kc * 10240 + threadIdx.x * 8;
    ushort_t* ldst = &sB[buf][threadIdx.x * 8];
#pragma unroll
    for (int p = 0; p < 5; p++) async_cp16(wsrc + p * 2048, ldst + p * 2048);
  };

  stage(0, 0);
  __syncthreads();

  floatx4 acc[2][10];
#pragma unroll
  for (int s = 0; s < 2; s++)
#pragma unroll
    for (int nt = 0; nt < 10; nt++) acc[s][nt] = (floatx4){0.f, 0.f, 0.f, 0.f};

#pragma unroll
  for (int kc = 0; kc < 5; kc++) {
    int buf = kc & 1;
    if (kc < 4) stage(buf ^ 1, kc + 1);
    bf16x8 a0 = make_frag(nf, ra, kc, quad);
    bf16x8 a1 = make_frag(nf, rb, kc, quad);
    const ushort_t* bp = &sB[buf][lane * 8];
#pragma unroll
    for (int nt = 0; nt < 10; nt++) {
      bf16x8 bh = *(const bf16x8*)(bp + (nt * 2) * 512);
      bf16x8 bl = *(const bf16x8*)(bp + (nt * 2 + 1) * 512);
      acc[0][nt] = __builtin_amdgcn_mfma_f32_16x16x32_bf16(a0, bh, acc[0][nt], 0, 0, 0);
      acc[1][nt] = __builtin_amdgcn_mfma_f32_16x16x32_bf16(a1, bh, acc[1][nt], 0, 0, 0);
      acc[0][nt] = __builtin_amdgcn_mfma_f32_16x16x32_bf16(a0, bl, acc[0][nt], 0, 0, 0);
      acc[1][nt] = __builtin_amdgcn_mfma_f32_16x16x32_bf16(a1, bl, acc[1][nt], 0, 0, 0);
    }
    __syncthreads();
  }

  float no[2][4];
#pragma unroll
  for (int s = 0; s < 2; s++)
#pragma unroll
    for (int r = 0; r < 4; r++) no[s][r] = norm_out[min(m0 + s * 16 + quad * 4 + r, N_NODES - 1)];

  // ---- pass 1: h cols 0..79 fp32 through LDS ----
  float* sF = (float*)&sB[0][0];   // 128 rows x 80 floats = 40 KB
#pragma unroll
  for (int nt = 0; nt < 5; nt++) {
    int c = nt * 16 + l16;
    float b = bias[c];
#pragma unroll
    for (int s = 0; s < 2; s++)
#pragma unroll
      for (int r = 0; r < 4; r++)
        sF[(wave * 32 + s * 16 + quad * 4 + r) * 80 + c] = acc[s][nt][r] + b;
  }
  __syncthreads();
#pragma unroll
  for (int i = 0; i < 10; i++) {
    int n = threadIdx.x + i * 256;
    int row = n / 20, ch = n - row * 20;
    int grow = blockIdx.x * 128 + row;
    if (grow < N_NODES)
      *((uint4*)(h + (size_t)grow * HPAD) + ch) = ((const uint4*)(sF + row * 80))[ch];
  }
  __syncthreads();
  // ---- pass 2: h cols 80..159 fp32 ----
#pragma unroll
  for (int nt = 5; nt < 10; nt++) {
    int c = nt * 16 + l16;
    float b = (c < DIM) ? bias[c] : 0.f;
#pragma unroll
    for (int s = 0; s < 2; s++)
#pragma unroll
      for (int r = 0; r < 4; r++)
        sF[(wave * 32 + s * 16 + quad * 4 + r) * 80 + (c - 80)] = acc[s][nt][r] + b;
  }
  __syncthreads();
#pragma unroll
  for (int i = 0; i < 10; i++) {
    int n = threadIdx.x + i * 256;
    int row = n / 20, ch = n - row * 20;
    int grow = blockIdx.x * 128 + row;
    if (grow < N_NODES)
      *((uint4*)(h + (size_t)grow * HPAD + 80) + ch) = ((const uint4*)(sF + row * 80))[ch];
  }
  __syncthreads();
  // ---- pass 3: hb bf16 (* norm_out) ----
  ushort_t* sC = &sB[0][0];   // 128 rows x 160 ushorts = 40 KB
#pragma unroll
  for (int nt = 0; nt < 10; nt++) {
    int c = nt * 16 + l16;
    float b = (c < DIM) ? bias[c] : 0.f;
#pragma unroll
    for (int s = 0; s < 2; s++)
#pragma unroll
      for (int r = 0; r < 4; r++)
        sC[(wave * 32 + s * 16 + quad * 4 + r) * 160 + c] = f2bf((acc[s][nt][r] + b) * no[s][r]);
  }
  __syncthreads();
#pragma unroll
  for (int i = 0; i < 10; i++) {
    int n = threadIdx.x + i * 256;
    int row = n / 20, ch = n - row * 20;
    int grow = blockIdx.x * 128 + row;
    if (grow < N_NODES)
      *((uint4*)(hb + (size_t)grow * APAD) + ch) = ((const uint4*)(sC + row * 160))[ch];
  }
}

// ------------- LAYER MFMA GEMM: single-bf16 W, 10 KB slices, A preloaded -------------
// 128 rows/block, 100 MFMAs/wave, 2x10KB double-buffered B, 2-half coalesced epilogue.
__global__ __launch_bounds__(256, 4) void gemm_kernel(
    const ushort_t* __restrict__ Abf, const ushort_t* __restrict__ Wh,
    const float* __restrict__ bias, const float* __restrict__ snorm,
    ushort_t* __restrict__ tmpb, float* __restrict__ stats) {
  __shared__ __align__(16) ushort_t sB[2][5120];    // 2 x 10 KB; epilogue reuses as 64x160
  __shared__ float sred[2 * DIM];
  int wave = threadIdx.x >> 6, lane = threadIdx.x & 63;
  int quad = lane >> 4, l16 = lane & 15;
  int m0 = blockIdx.x * 128 + wave * 32;
  int ra = min(m0 + l16, N_NODES - 1);
  int rb = min(m0 + 16 + l16, N_NODES - 1);
  const ushort_t* ap0 = Abf + (size_t)ra * APAD + quad * 8;
  const ushort_t* ap1 = Abf + (size_t)rb * APAD + quad * 8;

  // stage one 10 KB slice: 640 x 16 B chunks (256+256+128)
  auto stage = [&](int buf, int kc) {
    const ushort_t* wsrc = Wh + (size_t)kc * 5120;
    ushort_t* ldst = &sB[buf][0];
    async_cp16(wsrc + threadIdx.x * 8, ldst + threadIdx.x * 8);
    async_cp16(wsrc + (threadIdx.x + 256) * 8, ldst + (threadIdx.x + 256) * 8);
    if (threadIdx.x < 128)
      async_cp16(wsrc + (threadIdx.x + 512) * 8, ldst + (threadIdx.x + 512) * 8);
  };

  stage(0, 0);
  // preload all A fragments (independent 16 B loads, overlap with stage 0)
  bf16x8 a0[5], a1[5];
#pragma unroll
  for (int kc = 0; kc < 5; kc++) {
    a0[kc] = *(const bf16x8*)(ap0 + kc * 32);
    a1[kc] = *(const bf16x8*)(ap1 + kc * 32);
  }
  for (int i = threadIdx.x; i < 2 * DIM; i += 256) sred[i] = 0.f;
  __syncthreads();

  floatx4 acc[2][10];
#pragma unroll
  for (int s = 0; s < 2; s++)
#pragma unroll
    for (int nt = 0; nt < 10; nt++) acc[s][nt] = (floatx4){0.f, 0.f, 0.f, 0.f};

  for (int kc = 0; kc < 5; kc++) {
    int buf = kc & 1;
    if (kc < 4) stage(buf ^ 1, kc + 1);
    const ushort_t* bp = &sB[buf][lane * 8];
#pragma unroll
    for (int nt = 0; nt < 10; nt++) {
      bf16x8 bh = *(const bf16x8*)(bp + nt * 512);
      acc[0][nt] = __builtin_amdgcn_mfma_f32_16x16x32_bf16(a0[kc], bh, acc[0][nt], 0, 0, 0);
      acc[1][nt] = __builtin_amdgcn_mfma_f32_16x16x32_bf16(a1[kc], bh, acc[1][nt], 0, 0, 0);
    }
    __syncthreads();
  }

  // stats (fp32, pre-rounding of output is after scale; same value as stored)
  float sn[2][4];
#pragma unroll
  for (int s = 0; s < 2; s++)
#pragma unroll
    for (int r = 0; r < 4; r++) sn[s][r] = snorm[min(m0 + s * 16 + quad * 4 + r, N_NODES - 1)];
#pragma unroll
  for (int nt = 0; nt < 10; nt++) {
    int c = nt * 16 + l16;
    if (c < DIM) {
      float b = bias[c];
      float ssum = 0.f, ssq = 0.f;
#pragma unroll
      for (int s = 0; s < 2; s++)
#pragma unroll
        for (int r = 0; r < 4; r++) {
          if (m0 + s * 16 + quad * 4 + r < N_NODES) {
            float val = (acc[s][nt][r] + b) * sn[s][r];
            ssum += val; ssq += val * val;
          }
        }
      ssum += __shfl_xor(ssum, 16, 64); ssum += __shfl_xor(ssum, 32, 64);
      ssq  += __shfl_xor(ssq, 16, 64);  ssq  += __shfl_xor(ssq, 32, 64);
      if (quad == 0) {
        atomicAdd(&sred[c], ssum);
        atomicAdd(&sred[DIM + c], ssq);
      }
    }
  }

  // epilogue: two 64-row half passes through the 20 KB buffer (coalesced uint4 out)
  ushort_t* sC = &sB[0][0];   // 64 rows x 160 ushorts = 20 KB
#pragma unroll
  for (int half = 0; half < 2; half++) {
    __syncthreads();
    if ((wave >> 1) == half) {
      int lrow = (wave & 1) * 32;
#pragma unroll
      for (int nt = 0; nt < 10; nt++) {
        int c = nt * 16 + l16;
        float b = (c < DIM) ? bias[c] : 0.f;
#pragma unroll
        for (int s = 0; s < 2; s++)
#pragma unroll
          for (int r = 0; r < 4; r++)
            sC[(lrow + s * 16 + quad * 4 + r) * TPW + c] = f2bf((acc[s][nt][r] + b) * sn[s][r]);
      }
    }
    __syncthreads();
    uint4* gp = (uint4*)(tmpb + ((size_t)blockIdx.x * 128 + half * 64) * TPW);
#pragma unroll
    for (int i = 0; i < 5; i++) {
      int n = threadIdx.x + i * 256;
      gp[n] = *(const uint4*)(sC + n * 8);
    }
  }
  // partitioned global stat flush (sred complete: barriers above ordered it)
  float* stp = stats + (blockIdx.x & (ST_PART - 1)) * 2 * DIM;
  for (int i = threadIdx.x; i < 2 * DIM; i += 256) atomicAdd(&stp[i], sred[i]);
}

// ------- aggregation: one wave per destination node, bf16 gather, 4 edges in flight -------
__global__ __launch_bounds__(256) void agg_kernel(
    const ushort_t* __restrict__ hb, const int* __restrict__ row_ptr,
    const int* __restrict__ csr, const float* __restrict__ norm_in,
    ushort_t* __restrict__ xb) {
  int wid = threadIdx.x >> 6, lane = threadIdx.x & 63;
  int v = blockIdx.x * 4 + wid;
  if (v >= N_NODES) return;
  int e0 = row_ptr[v], e1 = row_ptr[v + 1];
  bool act = lane < 40;
  int col8 = lane * 4;  // ushort offset within row
  float a0 = 0.f, a1 = 0.f, a2 = 0.f, a3 = 0.f;
  float b0 = 0.f, b1 = 0.f, b2 = 0.f, b3 = 0.f;
  float c0 = 0.f, c1 = 0.f, c2 = 0.f, c3 = 0.f;
  float d0 = 0.f, d1 = 0.f, d2 = 0.f, d3 = 0.f;
  int e = e0;
  for (; e + 3 < e1; e += 4) {
    int s0 = csr[e], s1 = csr[e + 1], s2 = csr[e + 2], s3 = csr[e + 3];
    if (act) {
      uint2 u0 = *(const uint2*)(hb + (size_t)s0 * APAD + col8);
      uint2 u1 = *(const uint2*)(hb + (size_t)s1 * APAD + col8);
      uint2 u2 = *(const uint2*)(hb + (size_t)s2 * APAD + col8);
      uint2 u3 = *(const uint2*)(hb + (size_t)s3 * APAD + col8);
      a0 += bflo(u0.x); a1 += bfhi(u0.x); a2 += bflo(u0.y); a3 += bfhi(u0.y);
      b0 += bflo(u1.x); b1 += bfhi(u1.x); b2 += bflo(u1.y); b3 += bfhi(u1.y);
      c0 += bflo(u2.x); c1 += bfhi(u2.x); c2 += bflo(u2.y); c3 += bfhi(u2.y);
      d0 += bflo(u3.x); d1 += bfhi(u3.x); d2 += bflo(u3.y); d3 += bfhi(u3.y);
    }
  }
  for (; e < e1; e++) {
    int s0 = csr[e];
    if (act) {
      uint2 u0 = *(const uint2*)(hb + (size_t)s0 * APAD + col8);
      a0 += bflo(u0.x); a1 += bfhi(u0.x); a2 += bflo(u0.y); a3 += bfhi(u0.y);
    }
  }
  if (act) {
    float ni = norm_in[v];
    uint2 o;
    o.x = pack2bf((a0 + b0 + c0 + d0) * ni, (a1 + b1 + c1 + d1) * ni);
    o.y = pack2bf((a2 + b2 + c2 + d2) * ni, (a3 + b3 + c3 + d3) * ni);
    *(uint2*)((uint_t*)(xb + (size_t)v * APAD) + lane * 2) = o;
  }
}

// --- fused BN-prep + BN + ReLU + residual; reads bf16 tmp; writes h (fp32) + hb (bf16) ---
__global__ __launch_bounds__(256) void bn_kernel(const ushort_t* __restrict__ tmpb,
                                                 const float* __restrict__ stats,
                                                 const float* __restrict__ gamma,
                                                 const float* __restrict__ beta,
                                                 const float* __restrict__ norm_out,
                                                 float* __restrict__ h,
                                                 ushort_t* __restrict__ hb) {
  __shared__ float2 scs[DIM / 2], shs[DIM / 2];
  int t = threadIdx.x;
  if (t < DIM / 2) {
    int c0 = 2 * t, c1 = c0 + 1;
    float su0 = 0.f, su1 = 0.f, sq0 = 0.f, sq1 = 0.f;
#pragma unroll
    for (int p = 0; p < ST_PART; p++) {
      const float* sp = stats + p * 2 * DIM;
      su0 += sp[c0]; su1 += sp[c1];
      sq0 += sp[DIM + c0]; sq1 += sp[DIM + c1];
    }
    float mu0 = su0 * (1.f / N_NODES), mu1 = su1 * (1.f / N_NODES);
    float v0 = sq0 * (1.f / N_NODES) - mu0 * mu0;
    float v1 = sq1 * (1.f / N_NODES) - mu1 * mu1;
    float s0 = gamma[c0] * rsqrtf(v0 + BN_EPS), s1 = gamma[c1] * rsqrtf(v1 + BN_EPS);
    scs[t] = make_float2(s0, s1);
    shs[t] = make_float2(beta[c0] - mu0 * s0, beta[c1] - mu1 * s1);
  }
  __syncthreads();
  int idx = blockIdx.x * 256 + t;
  if (idx >= N_NODES * (DIM / 2)) return;
  int v = idx / (DIM / 2), c2 = idx - v * (DIM / 2);
  uint_t tu = ((const uint_t*)tmpb)[(size_t)v * (TPW / 2) + c2];
  float2 sc = scs[c2], sh = shs[c2];
  float2* hp = (float2*)(h + (size_t)v * HPAD + 2 * c2);
  float2 hv = *hp;
  float x0 = fmaf(bflo(tu), sc.x, sh.x); x0 = fmaxf(x0, 0.f);
  float x1 = fmaf(bfhi(tu), sc.y, sh.y); x1 = fmaxf(x1, 0.f);
  hv.x += x0; hv.y += x1;
  *hp = hv;
  float no = norm_out[v];
  ((uint_t*)hb)[(size_t)v * (APAD / 2) + c2] = pack2bf(hv.x * no, hv.y * no);
}

// ---------------- layer-3 fused: BN+ReLU+residual -> per-graph sum ----------------
__global__ __launch_bounds__(192) void gsum_kernel(
    const ushort_t* __restrict__ tmpb, const float* __restrict__ stats,
    const float* __restrict__ gamma, const float* __restrict__ beta,
    const float* __restrict__ h, const int* __restrict__ gids,
    float* __restrict__ hgp) {
  int t = threadIdx.x;
  if (t > DIM) return;
  float sc = 0.f, sh = 0.f;
  if (t < DIM) {
    float su = 0.f, sq = 0.f;
#pragma unroll
    for (int p = 0; p < ST_PART; p++) {
      const float* sp = stats + p * 2 * DIM;
      su += sp[t]; sq += sp[DIM + t];
    }
    float mu = su * (1.f / N_NODES);
    float var = sq * (1.f / N_NODES) - mu * mu;
    sc = gamma[t] * rsqrtf(var + BN_EPS);
    sh = beta[t] - mu * sc;
  }
  int r0 = blockIdx.x * 64;
  int part = blockIdx.x & (GS_PART - 1);
  float accv = 0.f;
  int g_prev = gids[r0];
  for (int rr = 0; rr < 64; rr++) {
    int r = r0 + rr;
    if (r >= N_NODES) break;
    int g = gids[r];
    if (g != g_prev) {
      atomicAdd(&hgp[(size_t)(part * N_GRAPHS + g_prev) * GS_STRIDE + t], accv);
      accv = 0.f; g_prev = g;
    }
    float val;
    if (t < DIM) {
      float x = fmaf(bf2f(tmpb[(size_t)r * TPW + t]), sc, sh);
      x = fmaxf(x, 0.f);
      val = h[(size_t)r * HPAD + t] + x;
    } else {
      val = 1.f;
    }
    accv += val;
  }
  atomicAdd(&hgp[(size_t)(part * N_GRAPHS + g_prev) * GS_STRIDE + t], accv);
}

// ---------------- fused mean + MLP readout: one block per graph ----------------
__global__ __launch_bounds__(256) void mlp_kernel(
    const float* __restrict__ hgp,
    const float* __restrict__ W1, const float* __restrict__ b1,
    const float* __restrict__ W2, const float* __restrict__ b2,
    const float* __restrict__ W3, const float* __restrict__ b3,
    float* __restrict__ out) {
  __shared__ float hrow[DIM];
  __shared__ float x1[73];
  __shared__ float x2[36];
  int g = blockIdx.x;
  int t = threadIdx.x;
  if (t < DIM) {
    float s = 0.f, cnt = 0.f;
#pragma unroll
    for (int p = 0; p < GS_PART; p++) {
      const float* row = hgp + (size_t)(p * N_GRAPHS + g) * GS_STRIDE;
      s += row[t];
      cnt += row[DIM];
    }
    hrow[t] = s / cnt;
  }
  __syncthreads();
  if (t < 73) {
    float s = b1[t];
    for (int k = 0; k < DIM; k++) s = fmaf(hrow[k], W1[k * 73 + t], s);
    x1[t] = s > 0.f ? s : 0.f;
  }
  __syncthreads();
  if (t < 36) {
    float s = b2[t];
    for (int k = 0; k < 73; k++) s = fmaf(x1[k], W2[k * 36 + t], s);
    x2[t] = s > 0.f ? s : 0.f;
  }
  __syncthreads();
  if (t < 10) {
    float s = b3[t];
    for (int k = 0; k < 36; k++) s = fmaf(x2[k], W3[k * 10 + t], s);
    out[g * 10 + t] = s;
  }
}

extern "C" void kernel_launch(void* const* d_in, const int* in_sizes, int n_in,
                              void* d_out, int out_size, void* d_ws, size_t ws_size,
                              hipStream_t stream) {
  const float* nodes_feat = (const float*)d_in[0];
  const float* snorm  = (const float*)d_in[1];
  const float* W_emb  = (const float*)d_in[2];
  const float* b_emb  = (const float*)d_in[3];
  const float* Ws     = (const float*)d_in[4];
  const float* bs     = (const float*)d_in[5];
  const float* gammas = (const float*)d_in[6];
  const float* betas  = (const float*)d_in[7];
  const float* W1 = (const float*)d_in[8];
  const float* b1 = (const float*)d_in[9];
  const float* W2 = (const float*)d_in[10];
  const float* b2 = (const float*)d_in[11];
  const float* W3 = (const float*)d_in[12];
  const float* b3 = (const float*)d_in[13];
  const int* src  = (const int*)d_in[14];
  const int* dst  = (const int*)d_in[15];
  const int* gids = (const int*)d_in[16];
  float* out = (float*)d_out;

  const int GB = (N_NODES + 127) / 128;        // 782 gemm blocks, 128 rows each
  const int NPADROWS = GB * 128;               // 100096

  char* base = (char*)d_ws;
  size_t off = 0;
  auto alloc = [&](size_t bytes) { void* p = base + off; off += (bytes + 255) & ~size_t(255); return p; };
  float* h    = (float*)alloc((size_t)N_NODES * HPAD * 4);
  ushort_t* tmpb = (ushort_t*)alloc((size_t)NPADROWS * TPW * 2);  // bf16 GEMM output
  ushort_t* xb = (ushort_t*)alloc((size_t)N_NODES * APAD * 2);    // bf16 GEMM input
  ushort_t* hb = (ushort_t*)alloc((size_t)N_NODES * APAD * 2);    // bf16 h * norm_out
  char* zstart = base + off;
  int* deg_out = (int*)alloc(N_NODES * 4);
  int* deg_in  = (int*)alloc(N_NODES * 4);
  int* fill    = (int*)alloc(N_NODES * 4);
  float* stats = (float*)alloc(4 * ST_PART * 2 * DIM * 4);  // per layer: ST_PART x [sum,sumsq]
  float* hgp   = (float*)alloc((size_t)GS_PART * N_GRAPHS * GS_STRIDE * 4);
  size_t zbytes = (size_t)((base + off) - zstart);
  int* row_ptr = (int*)alloc((N_NODES + 1) * 4);
  float* norm_out = (float*)alloc(N_NODES * 4);
  float* norm_in  = (float*)alloc(N_NODES * 4);
  int* csr   = (int*)alloc((size_t)N_EDGES * 4);
  int* bsums = (int*)alloc(128 * 4);
  int* bofs  = (int*)alloc(128 * 4);
  ushort_t* Wb = (ushort_t*)alloc((size_t)5 * 5 * 10 * 2 * 64 * 8 * 2);  // split hi/lo
  ushort_t* Wh = (ushort_t*)alloc((size_t)5 * 5 * 10 * 64 * 8 * 2);      // hi only

  hipMemsetAsync(zstart, 0, zbytes, stream);

  hist_kernel<<<(N_EDGES + 255) / 256, 256, 0, stream>>>(src, dst, deg_out, deg_in);
  norm_kernel<<<(N_NODES + 255) / 256, 256, 0, stream>>>(deg_out, deg_in, norm_out, norm_in);
  int nb = (N_NODES + 1023) / 1024;
  scan1_kernel<<<nb, 256, 0, stream>>>(deg_in, bsums);
  scan2_kernel<<<1, 64, 0, stream>>>(bsums, bofs, row_ptr, nb);
  scan3_kernel<<<nb, 256, 0, stream>>>(deg_in, bofs, row_ptr);
  csr_fill_kernel<<<(N_EDGES + 255) / 256, 256, 0, stream>>>(src, dst, row_ptr, fill, csr);
  wtrans_kernel<<<(5 * 5 * 10 * 64 * 8 + 255) / 256, 256, 0, stream>>>(W_emb, Ws, Wb, Wh);

  const size_t WHM = (size_t)5 * 10 * 64 * 8;      // Wh elems per matrix (25600)

  gemm_embed_kernel<<<GB, 256, 0, stream>>>(nodes_feat, Wb, b_emb, norm_out, h, hb);

  for (int l = 0; l < 4; l++) {
    float* st = stats + (size_t)l * ST_PART * 2 * DIM;
    agg_kernel<<<(N_NODES + 3) / 4, 256, 0, stream>>>(hb, row_ptr, csr, norm_in, xb);
    gemm_kernel<<<GB, 256, 0, stream>>>(xb, Wh + (size_t)(l + 1) * WHM, bs + l * DIM,
                                        snorm, tmpb, st);
    if (l < 3) {
      bn_kernel<<<(N_NODES * (DIM / 2) + 255) / 256, 256, 0, stream>>>(
          tmpb, st, gammas + l * DIM, betas + l * DIM, norm_out, h, hb);
    } else {
      gsum_kernel<<<(N_NODES + 63) / 64, 192, 0, stream>>>(
          tmpb, st, gammas + l * DIM, betas + l * DIM, h, gids, hgp);
    }
  }

  mlp_kernel<<<N_GRAPHS, 256, 0, stream>>>(hgp, W1, b1, W2, b2, W3, b3, out);
}

// Round 12
// 679.463 us; speedup vs baseline: 1.6072x; 1.0425x over previous
//
#include <hip/hip_runtime.h>

#define N_NODES 100000
#define N_EDGES 500000
#define N_GRAPHS 100
#define DIM 146
#define APAD 160        // padded bf16 row stride (16B-aligned, 5 k-chunks of 32)
#define TPW 160         // tmp bf16 row stride (ushorts)
#define BN_EPS 1e-5f
#define GS_PART 8
#define GS_STRIDE 147   // 146 cols + 1 count slot
#define ST_PART 4       // stat-atomic partitions

typedef __bf16 bf16x8 __attribute__((ext_vector_type(8)));
typedef float floatx4 __attribute__((ext_vector_type(4)));
typedef unsigned short ushort_t;
typedef unsigned int uint_t;

__device__ inline ushort_t f2bf(float x) {
  uint_t u = __float_as_uint(x);
  uint_t r = (u + 0x7fffu + ((u >> 16) & 1u)) >> 16;   // RNE
  return (ushort_t)r;
}
__device__ inline float bf2f(ushort_t b) { return __uint_as_float((uint_t)b << 16); }
__device__ inline uint_t pack2bf(float a, float b) {
  return (uint_t)f2bf(a) | ((uint_t)f2bf(b) << 16);
}
__device__ inline float bflo(uint_t u) { return __uint_as_float(u << 16); }
__device__ inline float bfhi(uint_t u) { return __uint_as_float(u & 0xffff0000u); }

// async global->LDS, 16 B per lane (global_load_lds_dwordx4)
__device__ inline void async_cp16(const ushort_t* g, ushort_t* l) {
  __builtin_amdgcn_global_load_lds((const __attribute__((address_space(1))) void*)g,
                                   (__attribute__((address_space(3))) void*)l, 16, 0, 0);
}

// ---------------- prep kernels ----------------
__global__ void hist_kernel(const int* __restrict__ src, const int* __restrict__ dst,
                            int* __restrict__ deg_out, int* __restrict__ deg_in) {
  int e = blockIdx.x * 256 + threadIdx.x;
  if (e < N_EDGES) {
    atomicAdd(&deg_out[src[e]], 1);
    atomicAdd(&deg_in[dst[e]], 1);
  }
}

__global__ void norm_kernel(const int* __restrict__ deg_out, const int* __restrict__ deg_in,
                            float* __restrict__ norm_out, float* __restrict__ norm_in) {
  int v = blockIdx.x * 256 + threadIdx.x;
  if (v < N_NODES) {
    norm_out[v] = rsqrtf((float)max(deg_out[v], 1));
    norm_in[v]  = rsqrtf((float)max(deg_in[v], 1));
  }
}

__global__ void scan1_kernel(const int* __restrict__ deg_in, int* __restrict__ bsums) {
  __shared__ int sred[256];
  int t0 = blockIdx.x * 1024 + threadIdx.x * 4;
  int s = 0;
#pragma unroll
  for (int i = 0; i < 4; i++) { int v = t0 + i; s += (v < N_NODES) ? deg_in[v] : 0; }
  sred[threadIdx.x] = s; __syncthreads();
  for (int off = 128; off > 0; off >>= 1) {
    if (threadIdx.x < off) sred[threadIdx.x] += sred[threadIdx.x + off];
    __syncthreads();
  }
  if (threadIdx.x == 0) bsums[blockIdx.x] = sred[0];
}

__global__ void scan2_kernel(const int* __restrict__ bsums, int* __restrict__ bofs,
                             int* __restrict__ row_ptr, int nb) {
  if (threadIdx.x == 0 && blockIdx.x == 0) {
    int run = 0;
    for (int i = 0; i < nb; i++) { bofs[i] = run; run += bsums[i]; }
    row_ptr[N_NODES] = run;
  }
}

__global__ void scan3_kernel(const int* __restrict__ deg_in, const int* __restrict__ bofs,
                             int* __restrict__ row_ptr) {
  __shared__ int ssc[256];
  int t0 = blockIdx.x * 1024 + threadIdx.x * 4;
  int v4[4]; int s = 0;
#pragma unroll
  for (int i = 0; i < 4; i++) { int v = t0 + i; v4[i] = (v < N_NODES) ? deg_in[v] : 0; s += v4[i]; }
  ssc[threadIdx.x] = s; __syncthreads();
  for (int off = 1; off < 256; off <<= 1) {
    int t = (threadIdx.x >= off) ? ssc[threadIdx.x - off] : 0;
    __syncthreads();
    ssc[threadIdx.x] += t;
    __syncthreads();
  }
  int ex = ssc[threadIdx.x] - s + bofs[blockIdx.x];
#pragma unroll
  for (int i = 0; i < 4; i++) {
    int v = t0 + i;
    if (v < N_NODES) { row_ptr[v] = ex; ex += v4[i]; }
  }
}

__global__ void csr_fill_kernel(const int* __restrict__ src, const int* __restrict__ dst,
                                const int* __restrict__ row_ptr, int* __restrict__ fill,
                                int* __restrict__ csr) {
  int e = blockIdx.x * 256 + threadIdx.x;
  if (e < N_EDGES) {
    int d = dst[e];
    int slot = atomicAdd(&fill[d], 1);
    csr[row_ptr[d] + slot] = src[e];
  }
}

// ---------- W swizzle into MFMA B-fragment order (single bf16, 10 KB per (m,kc)) ----------
__global__ void wtrans_kernel(const float* __restrict__ W_emb, const float* __restrict__ Ws,
                              ushort_t* __restrict__ Wh) {
  int idx = blockIdx.x * 256 + threadIdx.x;
  if (idx >= 5 * 5 * 10 * 64 * 8) return;
  int j = idx & 7;
  int t = idx >> 3;
  int lane = t & 63; t >>= 6;
  int nt = t % 10; t /= 10;
  int kc = t % 5;
  int m = t / 5;
  const float* W = (m == 0) ? W_emb : Ws + (size_t)(m - 1) * DIM * DIM;
  int k = kc * 32 + (lane >> 4) * 8 + j;
  int n = nt * 16 + (lane & 15);
  float w = (k < DIM && n < DIM) ? W[k * DIM + n] : 0.f;
  Wh[(size_t)(((m * 5 + kc) * 10 + nt) * 64 + lane) * 8 + j] = f2bf(w);
}

// in-register A-fragment from fp32 row (RNE pack)
__device__ inline bf16x8 make_frag(const float* __restrict__ nf, int row, int kc, int quad) {
  union { bf16x8 v; ushort_t u[8]; } r;
  const float* p = nf + (size_t)row * DIM + kc * 32 + quad * 8;
  int c0 = kc * 32 + quad * 8;
  if (c0 + 8 <= DIM) {
    float2 q0 = *(const float2*)(p);
    float2 q1 = *(const float2*)(p + 2);
    float2 q2 = *(const float2*)(p + 4);
    float2 q3 = *(const float2*)(p + 6);
    r.u[0] = f2bf(q0.x); r.u[1] = f2bf(q0.y); r.u[2] = f2bf(q1.x); r.u[3] = f2bf(q1.y);
    r.u[4] = f2bf(q2.x); r.u[5] = f2bf(q2.y); r.u[6] = f2bf(q3.x); r.u[7] = f2bf(q3.y);
  } else {
#pragma unroll
    for (int j = 0; j < 8; j++) r.u[j] = (c0 + j < DIM) ? f2bf(p[j]) : (ushort_t)0;
  }
  return r.v;
}

// ------------- embedding GEMM: fp32 A in-register, hi-only W, bf16 residual out -------------
__global__ __launch_bounds__(256, 4) void gemm_embed_kernel(
    const float* __restrict__ nf, const ushort_t* __restrict__ Wh,
    const float* __restrict__ bias, ushort_t* __restrict__ hbf) {
  __shared__ __align__(16) ushort_t sB[2][5120];   // 2 x 10 KB; epilogue reuses as 64x160
  int wave = threadIdx.x >> 6, lane = threadIdx.x & 63;
  int quad = lane >> 4, l16 = lane & 15;
  int m0 = blockIdx.x * 128 + wave * 32;
  int ra = min(m0 + l16, N_NODES - 1);
  int rb = min(m0 + 16 + l16, N_NODES - 1);

  auto stage = [&](int buf, int kc) {
    const ushort_t* wsrc = Wh + (size_t)kc * 5120;
    ushort_t* ldst = &sB[buf][0];
    async_cp16(wsrc + threadIdx.x * 8, ldst + threadIdx.x * 8);
    async_cp16(wsrc + (threadIdx.x + 256) * 8, ldst + (threadIdx.x + 256) * 8);
    if (threadIdx.x < 128)
      async_cp16(wsrc + (threadIdx.x + 512) * 8, ldst + (threadIdx.x + 512) * 8);
  };

  stage(0, 0);
  __syncthreads();

  floatx4 acc[2][10];
#pragma unroll
  for (int s = 0; s < 2; s++)
#pragma unroll
    for (int nt = 0; nt < 10; nt++) acc[s][nt] = (floatx4){0.f, 0.f, 0.f, 0.f};

  for (int kc = 0; kc < 5; kc++) {
    int buf = kc & 1;
    if (kc < 4) stage(buf ^ 1, kc + 1);
    bf16x8 a0 = make_frag(nf, ra, kc, quad);
    bf16x8 a1 = make_frag(nf, rb, kc, quad);
    const ushort_t* bp = &sB[buf][lane * 8];
#pragma unroll
    for (int nt = 0; nt < 10; nt++) {
      bf16x8 bh = *(const bf16x8*)(bp + nt * 512);
      acc[0][nt] = __builtin_amdgcn_mfma_f32_16x16x32_bf16(a0, bh, acc[0][nt], 0, 0, 0);
      acc[1][nt] = __builtin_amdgcn_mfma_f32_16x16x32_bf16(a1, bh, acc[1][nt], 0, 0, 0);
    }
    __syncthreads();
  }

  // epilogue: two 64-row half passes, coalesced bf16 writes (pad cols = 0 via zeroed W)
  ushort_t* sC = &sB[0][0];   // 64 rows x 160 ushorts = 20 KB
#pragma unroll
  for (int half = 0; half < 2; half++) {
    __syncthreads();
    if ((wave >> 1) == half) {
      int lrow = (wave & 1) * 32;
#pragma unroll
      for (int nt = 0; nt < 10; nt++) {
        int c = nt * 16 + l16;
        float b = (c < DIM) ? bias[c] : 0.f;
#pragma unroll
        for (int s = 0; s < 2; s++)
#pragma unroll
          for (int r = 0; r < 4; r++)
            sC[(lrow + s * 16 + quad * 4 + r) * 160 + c] = f2bf(acc[s][nt][r] + b);
      }
    }
    __syncthreads();
    uint4* gp = (uint4*)(hbf + ((size_t)blockIdx.x * 128 + half * 64) * APAD);
#pragma unroll
    for (int i = 0; i < 5; i++) {
      int n = threadIdx.x + i * 256;
      gp[n] = *(const uint4*)(sC + n * 8);
    }
  }
}

// ------------- LAYER MFMA GEMM: single-bf16 W, 10 KB slices, A preloaded -------------
__global__ __launch_bounds__(256, 4) void gemm_kernel(
    const ushort_t* __restrict__ Abf, const ushort_t* __restrict__ Wh,
    const float* __restrict__ bias, const float* __restrict__ snorm,
    ushort_t* __restrict__ tmpb, float* __restrict__ stats) {
  __shared__ __align__(16) ushort_t sB[2][5120];    // 2 x 10 KB; epilogue reuses as 64x160
  __shared__ float sred[2 * DIM];
  int wave = threadIdx.x >> 6, lane = threadIdx.x & 63;
  int quad = lane >> 4, l16 = lane & 15;
  int m0 = blockIdx.x * 128 + wave * 32;
  int ra = min(m0 + l16, N_NODES - 1);
  int rb = min(m0 + 16 + l16, N_NODES - 1);
  const ushort_t* ap0 = Abf + (size_t)ra * APAD + quad * 8;
  const ushort_t* ap1 = Abf + (size_t)rb * APAD + quad * 8;

  auto stage = [&](int buf, int kc) {
    const ushort_t* wsrc = Wh + (size_t)kc * 5120;
    ushort_t* ldst = &sB[buf][0];
    async_cp16(wsrc + threadIdx.x * 8, ldst + threadIdx.x * 8);
    async_cp16(wsrc + (threadIdx.x + 256) * 8, ldst + (threadIdx.x + 256) * 8);
    if (threadIdx.x < 128)
      async_cp16(wsrc + (threadIdx.x + 512) * 8, ldst + (threadIdx.x + 512) * 8);
  };

  stage(0, 0);
  bf16x8 a0[5], a1[5];
#pragma unroll
  for (int kc = 0; kc < 5; kc++) {
    a0[kc] = *(const bf16x8*)(ap0 + kc * 32);
    a1[kc] = *(const bf16x8*)(ap1 + kc * 32);
  }
  for (int i = threadIdx.x; i < 2 * DIM; i += 256) sred[i] = 0.f;
  __syncthreads();

  floatx4 acc[2][10];
#pragma unroll
  for (int s = 0; s < 2; s++)
#pragma unroll
    for (int nt = 0; nt < 10; nt++) acc[s][nt] = (floatx4){0.f, 0.f, 0.f, 0.f};

  for (int kc = 0; kc < 5; kc++) {
    int buf = kc & 1;
    if (kc < 4) stage(buf ^ 1, kc + 1);
    const ushort_t* bp = &sB[buf][lane * 8];
#pragma unroll
    for (int nt = 0; nt < 10; nt++) {
      bf16x8 bh = *(const bf16x8*)(bp + nt * 512);
      acc[0][nt] = __builtin_amdgcn_mfma_f32_16x16x32_bf16(a0[kc], bh, acc[0][nt], 0, 0, 0);
      acc[1][nt] = __builtin_amdgcn_mfma_f32_16x16x32_bf16(a1[kc], bh, acc[1][nt], 0, 0, 0);
    }
    __syncthreads();
  }

  float sn[2][4];
#pragma unroll
  for (int s = 0; s < 2; s++)
#pragma unroll
    for (int r = 0; r < 4; r++) sn[s][r] = snorm[min(m0 + s * 16 + quad * 4 + r, N_NODES - 1)];
#pragma unroll
  for (int nt = 0; nt < 10; nt++) {
    int c = nt * 16 + l16;
    if (c < DIM) {
      float b = bias[c];
      float ssum = 0.f, ssq = 0.f;
#pragma unroll
      for (int s = 0; s < 2; s++)
#pragma unroll
        for (int r = 0; r < 4; r++) {
          if (m0 + s * 16 + quad * 4 + r < N_NODES) {
            float val = (acc[s][nt][r] + b) * sn[s][r];
            ssum += val; ssq += val * val;
          }
        }
      ssum += __shfl_xor(ssum, 16, 64); ssum += __shfl_xor(ssum, 32, 64);
      ssq  += __shfl_xor(ssq, 16, 64);  ssq  += __shfl_xor(ssq, 32, 64);
      if (quad == 0) {
        atomicAdd(&sred[c], ssum);
        atomicAdd(&sred[DIM + c], ssq);
      }
    }
  }

  ushort_t* sC = &sB[0][0];   // 64 rows x 160 ushorts = 20 KB
#pragma unroll
  for (int half = 0; half < 2; half++) {
    __syncthreads();
    if ((wave >> 1) == half) {
      int lrow = (wave & 1) * 32;
#pragma unroll
      for (int nt = 0; nt < 10; nt++) {
        int c = nt * 16 + l16;
        float b = (c < DIM) ? bias[c] : 0.f;
#pragma unroll
        for (int s = 0; s < 2; s++)
#pragma unroll
          for (int r = 0; r < 4; r++)
            sC[(lrow + s * 16 + quad * 4 + r) * TPW + c] = f2bf((acc[s][nt][r] + b) * sn[s][r]);
      }
    }
    __syncthreads();
    uint4* gp = (uint4*)(tmpb + ((size_t)blockIdx.x * 128 + half * 64) * TPW);
#pragma unroll
    for (int i = 0; i < 5; i++) {
      int n = threadIdx.x + i * 256;
      gp[n] = *(const uint4*)(sC + n * 8);
    }
  }
  float* stp = stats + (blockIdx.x & (ST_PART - 1)) * 2 * DIM;
  for (int i = threadIdx.x; i < 2 * DIM; i += 256) atomicAdd(&stp[i], sred[i]);
}

// ------- aggregation: one wave per node, bf16 gather, per-edge norm_out scale, 4-deep -------
__global__ __launch_bounds__(256) void agg_kernel(
    const ushort_t* __restrict__ hbf, const int* __restrict__ row_ptr,
    const int* __restrict__ csr, const float* __restrict__ norm_out,
    const float* __restrict__ norm_in, ushort_t* __restrict__ xb) {
  int wid = threadIdx.x >> 6, lane = threadIdx.x & 63;
  int v = blockIdx.x * 4 + wid;
  if (v >= N_NODES) return;
  int e0 = row_ptr[v], e1 = row_ptr[v + 1];
  bool act = lane < 40;
  int col8 = lane * 4;  // ushort offset within row
  float a0 = 0.f, a1 = 0.f, a2 = 0.f, a3 = 0.f;
  float b0 = 0.f, b1 = 0.f, b2 = 0.f, b3 = 0.f;
  float c0 = 0.f, c1 = 0.f, c2 = 0.f, c3 = 0.f;
  float d0 = 0.f, d1 = 0.f, d2 = 0.f, d3 = 0.f;
  int e = e0;
  for (; e + 3 < e1; e += 4) {
    int s0 = csr[e], s1 = csr[e + 1], s2 = csr[e + 2], s3 = csr[e + 3];
    float n0 = norm_out[s0], n1 = norm_out[s1], n2 = norm_out[s2], n3 = norm_out[s3];
    if (act) {
      uint2 u0 = *(const uint2*)(hbf + (size_t)s0 * APAD + col8);
      uint2 u1 = *(const uint2*)(hbf + (size_t)s1 * APAD + col8);
      uint2 u2 = *(const uint2*)(hbf + (size_t)s2 * APAD + col8);
      uint2 u3 = *(const uint2*)(hbf + (size_t)s3 * APAD + col8);
      a0 = fmaf(bflo(u0.x), n0, a0); a1 = fmaf(bfhi(u0.x), n0, a1);
      a2 = fmaf(bflo(u0.y), n0, a2); a3 = fmaf(bfhi(u0.y), n0, a3);
      b0 = fmaf(bflo(u1.x), n1, b0); b1 = fmaf(bfhi(u1.x), n1, b1);
      b2 = fmaf(bflo(u1.y), n1, b2); b3 = fmaf(bfhi(u1.y), n1, b3);
      c0 = fmaf(bflo(u2.x), n2, c0); c1 = fmaf(bfhi(u2.x), n2, c1);
      c2 = fmaf(bflo(u2.y), n2, c2); c3 = fmaf(bfhi(u2.y), n2, c3);
      d0 = fmaf(bflo(u3.x), n3, d0); d1 = fmaf(bfhi(u3.x), n3, d1);
      d2 = fmaf(bflo(u3.y), n3, d2); d3 = fmaf(bfhi(u3.y), n3, d3);
    }
  }
  for (; e < e1; e++) {
    int s0 = csr[e];
    float n0 = norm_out[s0];
    if (act) {
      uint2 u0 = *(const uint2*)(hbf + (size_t)s0 * APAD + col8);
      a0 = fmaf(bflo(u0.x), n0, a0); a1 = fmaf(bfhi(u0.x), n0, a1);
      a2 = fmaf(bflo(u0.y), n0, a2); a3 = fmaf(bfhi(u0.y), n0, a3);
    }
  }
  if (act) {
    float ni = norm_in[v];
    uint2 o;
    o.x = pack2bf((a0 + b0 + c0 + d0) * ni, (a1 + b1 + c1 + d1) * ni);
    o.y = pack2bf((a2 + b2 + c2 + d2) * ni, (a3 + b3 + c3 + d3) * ni);
    *(uint2*)((uint_t*)(xb + (size_t)v * APAD) + lane * 2) = o;
  }
}

// --- fused BN-prep + BN + ReLU + residual; bf16 in/out (stats fp32) ---
__global__ __launch_bounds__(256) void bn_kernel(const ushort_t* __restrict__ tmpb,
                                                 const float* __restrict__ stats,
                                                 const float* __restrict__ gamma,
                                                 const float* __restrict__ beta,
                                                 ushort_t* __restrict__ hbf) {
  __shared__ float2 scs[DIM / 2], shs[DIM / 2];
  int t = threadIdx.x;
  if (t < DIM / 2) {
    int c0 = 2 * t, c1 = c0 + 1;
    float su0 = 0.f, su1 = 0.f, sq0 = 0.f, sq1 = 0.f;
#pragma unroll
    for (int p = 0; p < ST_PART; p++) {
      const float* sp = stats + p * 2 * DIM;
      su0 += sp[c0]; su1 += sp[c1];
      sq0 += sp[DIM + c0]; sq1 += sp[DIM + c1];
    }
    float mu0 = su0 * (1.f / N_NODES), mu1 = su1 * (1.f / N_NODES);
    float v0 = sq0 * (1.f / N_NODES) - mu0 * mu0;
    float v1 = sq1 * (1.f / N_NODES) - mu1 * mu1;
    float s0 = gamma[c0] * rsqrtf(v0 + BN_EPS), s1 = gamma[c1] * rsqrtf(v1 + BN_EPS);
    scs[t] = make_float2(s0, s1);
    shs[t] = make_float2(beta[c0] - mu0 * s0, beta[c1] - mu1 * s1);
  }
  __syncthreads();
  int idx = blockIdx.x * 256 + t;
  if (idx >= N_NODES * (DIM / 2)) return;
  int v = idx / (DIM / 2), c2 = idx - v * (DIM / 2);
  uint_t tu = ((const uint_t*)tmpb)[(size_t)v * (TPW / 2) + c2];
  uint_t hu = ((const uint_t*)hbf)[(size_t)v * (APAD / 2) + c2];
  float2 sc = scs[c2], sh = shs[c2];
  float x0 = fmaf(bflo(tu), sc.x, sh.x); x0 = fmaxf(x0, 0.f);
  float x1 = fmaf(bfhi(tu), sc.y, sh.y); x1 = fmaxf(x1, 0.f);
  ((uint_t*)hbf)[(size_t)v * (APAD / 2) + c2] = pack2bf(bflo(hu) + x0, bfhi(hu) + x1);
}

// ---------------- layer-3 fused: BN+ReLU+residual -> per-graph sum ----------------
__global__ __launch_bounds__(192) void gsum_kernel(
    const ushort_t* __restrict__ tmpb, const float* __restrict__ stats,
    const float* __restrict__ gamma, const float* __restrict__ beta,
    const ushort_t* __restrict__ hbf, const int* __restrict__ gids,
    float* __restrict__ hgp) {
  int t = threadIdx.x;
  if (t > DIM) return;
  float sc = 0.f, sh = 0.f;
  if (t < DIM) {
    float su = 0.f, sq = 0.f;
#pragma unroll
    for (int p = 0; p < ST_PART; p++) {
      const float* sp = stats + p * 2 * DIM;
      su += sp[t]; sq += sp[DIM + t];
    }
    float mu = su * (1.f / N_NODES);
    float var = sq * (1.f / N_NODES) - mu * mu;
    sc = gamma[t] * rsqrtf(var + BN_EPS);
    sh = beta[t] - mu * sc;
  }
  int r0 = blockIdx.x * 64;
  int part = blockIdx.x & (GS_PART - 1);
  float accv = 0.f;
  int g_prev = gids[r0];
  for (int rr = 0; rr < 64; rr++) {
    int r = r0 + rr;
    if (r >= N_NODES) break;
    int g = gids[r];
    if (g != g_prev) {
      atomicAdd(&hgp[(size_t)(part * N_GRAPHS + g_prev) * GS_STRIDE + t], accv);
      accv = 0.f; g_prev = g;
    }
    float val;
    if (t < DIM) {
      float x = fmaf(bf2f(tmpb[(size_t)r * TPW + t]), sc, sh);
      x = fmaxf(x, 0.f);
      val = bf2f(hbf[(size_t)r * APAD + t]) + x;
    } else {
      val = 1.f;
    }
    accv += val;
  }
  atomicAdd(&hgp[(size_t)(part * N_GRAPHS + g_prev) * GS_STRIDE + t], accv);
}

// ---------------- fused mean + MLP readout: one block per graph ----------------
__global__ __launch_bounds__(256) void mlp_kernel(
    const float* __restrict__ hgp,
    const float* __restrict__ W1, const float* __restrict__ b1,
    const float* __restrict__ W2, const float* __restrict__ b2,
    const float* __restrict__ W3, const float* __restrict__ b3,
    float* __restrict__ out) {
  __shared__ float hrow[DIM];
  __shared__ float x1[73];
  __shared__ float x2[36];
  int g = blockIdx.x;
  int t = threadIdx.x;
  if (t < DIM) {
    float s = 0.f, cnt = 0.f;
#pragma unroll
    for (int p = 0; p < GS_PART; p++) {
      const float* row = hgp + (size_t)(p * N_GRAPHS + g) * GS_STRIDE;
      s += row[t];
      cnt += row[DIM];
    }
    hrow[t] = s / cnt;
  }
  __syncthreads();
  if (t < 73) {
    float s = b1[t];
    for (int k = 0; k < DIM; k++) s = fmaf(hrow[k], W1[k * 73 + t], s);
    x1[t] = s > 0.f ? s : 0.f;
  }
  __syncthreads();
  if (t < 36) {
    float s = b2[t];
    for (int k = 0; k < 73; k++) s = fmaf(x1[k], W2[k * 36 + t], s);
    x2[t] = s > 0.f ? s : 0.f;
  }
  __syncthreads();
  if (t < 10) {
    float s = b3[t];
    for (int k = 0; k < 36; k++) s = fmaf(x2[k], W3[k * 10 + t], s);
    out[g * 10 + t] = s;
  }
}

extern "C" void kernel_launch(void* const* d_in, const int* in_sizes, int n_in,
                              void* d_out, int out_size, void* d_ws, size_t ws_size,
                              hipStream_t stream) {
  const float* nodes_feat = (const float*)d_in[0];
  const float* snorm  = (const float*)d_in[1];
  const float* W_emb  = (const float*)d_in[2];
  const float* b_emb  = (const float*)d_in[3];
  const float* Ws     = (const float*)d_in[4];
  const float* bs     = (const float*)d_in[5];
  const float* gammas = (const float*)d_in[6];
  const float* betas  = (const float*)d_in[7];
  const float* W1 = (const float*)d_in[8];
  const float* b1 = (const float*)d_in[9];
  const float* W2 = (const float*)d_in[10];
  const float* b2 = (const float*)d_in[11];
  const float* W3 = (const float*)d_in[12];
  const float* b3 = (const float*)d_in[13];
  const int* src  = (const int*)d_in[14];
  const int* dst  = (const int*)d_in[15];
  const int* gids = (const int*)d_in[16];
  float* out = (float*)d_out;

  const int GB = (N_NODES + 127) / 128;        // 782 gemm blocks, 128 rows each
  const int NPADROWS = GB * 128;               // 100096

  char* base = (char*)d_ws;
  size_t off = 0;
  auto alloc = [&](size_t bytes) { void* p = base + off; off += (bytes + 255) & ~size_t(255); return p; };
  ushort_t* hbf  = (ushort_t*)alloc((size_t)NPADROWS * APAD * 2);  // bf16 residual stream
  ushort_t* tmpb = (ushort_t*)alloc((size_t)NPADROWS * TPW * 2);   // bf16 GEMM output
  ushort_t* xb   = (ushort_t*)alloc((size_t)N_NODES * APAD * 2);   // bf16 GEMM input
  char* zstart = base + off;
  int* deg_out = (int*)alloc(N_NODES * 4);
  int* deg_in  = (int*)alloc(N_NODES * 4);
  int* fill    = (int*)alloc(N_NODES * 4);
  float* stats = (float*)alloc(4 * ST_PART * 2 * DIM * 4);  // per layer: ST_PART x [sum,sumsq]
  float* hgp   = (float*)alloc((size_t)GS_PART * N_GRAPHS * GS_STRIDE * 4);
  size_t zbytes = (size_t)((base + off) - zstart);
  int* row_ptr = (int*)alloc((N_NODES + 1) * 4);
  float* norm_out = (float*)alloc(N_NODES * 4);
  float* norm_in  = (float*)alloc(N_NODES * 4);
  int* csr   = (int*)alloc((size_t)N_EDGES * 4);
  int* bsums = (int*)alloc(128 * 4);
  int* bofs  = (int*)alloc(128 * 4);
  ushort_t* Wh = (ushort_t*)alloc((size_t)5 * 5 * 10 * 64 * 8 * 2);  // single bf16

  hipMemsetAsync(zstart, 0, zbytes, stream);

  hist_kernel<<<(N_EDGES + 255) / 256, 256, 0, stream>>>(src, dst, deg_out, deg_in);
  norm_kernel<<<(N_NODES + 255) / 256, 256, 0, stream>>>(deg_out, deg_in, norm_out, norm_in);
  int nb = (N_NODES + 1023) / 1024;
  scan1_kernel<<<nb, 256, 0, stream>>>(deg_in, bsums);
  scan2_kernel<<<1, 64, 0, stream>>>(bsums, bofs, row_ptr, nb);
  scan3_kernel<<<nb, 256, 0, stream>>>(deg_in, bofs, row_ptr);
  csr_fill_kernel<<<(N_EDGES + 255) / 256, 256, 0, stream>>>(src, dst, row_ptr, fill, csr);
  wtrans_kernel<<<(5 * 5 * 10 * 64 * 8 + 255) / 256, 256, 0, stream>>>(W_emb, Ws, Wh);

  const size_t WHM = (size_t)5 * 10 * 64 * 8;      // Wh elems per matrix (25600)

  gemm_embed_kernel<<<GB, 256, 0, stream>>>(nodes_feat, Wh, b_emb, hbf);

  for (int l = 0; l < 4; l++) {
    float* st = stats + (size_t)l * ST_PART * 2 * DIM;
    agg_kernel<<<(N_NODES + 3) / 4, 256, 0, stream>>>(hbf, row_ptr, csr, norm_out, norm_in, xb);
    gemm_kernel<<<GB, 256, 0, stream>>>(xb, Wh + (size_t)(l + 1) * WHM, bs + l * DIM,
                                        snorm, tmpb, st);
    if (l < 3) {
      bn_kernel<<<(N_NODES * (DIM / 2) + 255) / 256, 256, 0, stream>>>(
          tmpb, st, gammas + l * DIM, betas + l * DIM, hbf);
    } else {
      gsum_kernel<<<(N_NODES + 63) / 64, 192, 0, stream>>>(
          tmpb, st, gammas + l * DIM, betas + l * DIM, hbf, gids, hgp);
    }
  }

  mlp_kernel<<<N_GRAPHS, 256, 0, stream>>>(hgp, W1, b1, W2, b2, W3, b3, out);
}